// Round 1
// baseline (1627.304 us; speedup 1.0000x reference)
//
#include <hip/hip_runtime.h>
#include <math.h>

#define B_ 2
#define T_ 2048
#define C_ 1024
#define H_ 16
#define D_ 64

// rows-per-wave / q-rows per block for attention
#define RPW 4
#define QB 16

// ---------------------------------------------------------------------------
// GEMM (NT): C[m][n] = sum_k A[m][k] * B[n][k]
// A: MxK row-major, B: NxK row-major, C: MxN row-major.
// 64x64 tile, BK=32, 256 threads, 4x4 micro-tile per thread.
// ---------------------------------------------------------------------------
__global__ __launch_bounds__(256) void gemm_nt_f32(
    const float* __restrict__ A, const float* __restrict__ B,
    float* __restrict__ C, int M, int N, int K)
{
  __shared__ float As[32][68];   // [k][m], row stride 68 floats = 272B (16B aligned)
  __shared__ float Bs[32][68];   // [k][n]
  const int bm = blockIdx.y * 64;
  const int bn = blockIdx.x * 64;
  const int tid = threadIdx.x;
  const int tx = tid & 15, ty = tid >> 4;
  const float* Ab = A + (size_t)bm * K;
  const float* Bb = B + (size_t)bn * K;
  float acc[4][4] = {};

  for (int k0 = 0; k0 < K; k0 += 32) {
    #pragma unroll
    for (int i = 0; i < 8; i++) {
      int idx = tid + (i << 8);
      int r = idx >> 5, c = idx & 31;          // r: 0..63 row, c: 0..31 k
      As[c][r] = Ab[(size_t)r * K + (k0 + c)];
      Bs[c][r] = Bb[(size_t)r * K + (k0 + c)];
    }
    __syncthreads();
    #pragma unroll
    for (int k = 0; k < 32; k++) {
      const float4 a4 = *(const float4*)&As[k][ty * 4];
      const float4 b4 = *(const float4*)&Bs[k][tx * 4];
      const float av[4] = {a4.x, a4.y, a4.z, a4.w};
      const float bv[4] = {b4.x, b4.y, b4.z, b4.w};
      #pragma unroll
      for (int i = 0; i < 4; i++)
        #pragma unroll
        for (int j = 0; j < 4; j++)
          acc[i][j] = fmaf(av[i], bv[j], acc[i][j]);
    }
    __syncthreads();
  }

  #pragma unroll
  for (int i = 0; i < 4; i++)
    #pragma unroll
    for (int j = 0; j < 4; j++)
      C[(size_t)(bm + ty * 4 + i) * N + (bn + tx * 4 + j)] = acc[i][j];
}

// ---------------------------------------------------------------------------
// Apply softplus in place to the q and k thirds of qkv (B,T,3C).
// idx covers B*T*2048 elements; c in [0,2048) maps to row offset [0,2048).
// ---------------------------------------------------------------------------
__global__ __launch_bounds__(256) void softplus_inplace(float* __restrict__ qkv)
{
  int idx = blockIdx.x * 256 + threadIdx.x;         // < B_*T_*2048
  size_t off = ((size_t)(idx >> 11)) * 3072 + (idx & 2047);
  float v = qkv[off];
  // softplus(v) = max(v,0) + log1p(exp(-|v|))
  qkv[off] = fmaxf(v, 0.f) + log1pf(expf(-fabsf(v)));
}

// ---------------------------------------------------------------------------
// Tables: postab[t][d] = (cos(t*invf_d), sin(t*invf_d))   (T*64 float2)
//         dtab[h][d]   = (cos(clip(delta)), sin(clip(delta)))  (H*64 float2)
// ---------------------------------------------------------------------------
__global__ __launch_bounds__(256) void build_tables(
    float* __restrict__ postab, float* __restrict__ dtab,
    const float* __restrict__ delta)
{
  int idx = blockIdx.x * 256 + threadIdx.x;   // < T_*64
  int t = idx >> 6, d = idx & 63;
  float invf = powf(10000.f, -(float)d * (1.0f / 64.0f));
  float ang = (float)t * invf;
  float sp, cp;
  sincosf(ang, &sp, &cp);
  postab[idx * 2 + 0] = cp;
  postab[idx * 2 + 1] = sp;
  if (idx < H_ * 64) {
    float dl = delta[idx];
    dl = fminf(fmaxf(dl, -6.2831853071795865f), 0.f);
    float sd, cd;
    sincosf(dl, &sd, &cd);
    dtab[idx * 2 + 0] = cd;
    dtab[idx * 2 + 1] = sd;
  }
}

// ---------------------------------------------------------------------------
// Causal attention with PoPE phases fused into tile staging.
// Block: 256 threads = 4 waves; each wave owns RPW=4 q-rows (QB=16 per block).
// Per s-tile (64 keys): stage K(128-dim cat) and V(64) in LDS; lane = s for
// QK^T; lane = output dim d for PV. Online softmax per row via wave shuffles.
// qkv q/k thirds hold softplus(mu) already.
// ---------------------------------------------------------------------------
__global__ __launch_bounds__(256) void attn_f32(
    const float* __restrict__ qkv,     // (B,T,3072), q/k pre-softplus'd
    const float* __restrict__ postab,  // (T,64,2)
    const float* __restrict__ dtab,    // (H,64,2)
    float* __restrict__ y)             // (B,T,1024)
{
  const int qt = blockIdx.x, h = blockIdx.y, b = blockIdx.z;
  const int tid = threadIdx.x;
  const int w = tid >> 6, lane = tid & 63;
  const int t0 = qt * QB;

  __shared__ float Qst[128][16];   // [d][row] - broadcast float4 reads
  __shared__ float Ks[64][129];    // [s][d]   - (lane+d)%32 banks, conflict-free
  __shared__ float Vs[64][65];     // [s][d]
  __shared__ float Pst[64][20];    // [s][row] - broadcast float4 reads

  const size_t base = (size_t)b * T_ * 3072 + (size_t)h * 64;
  const float* qmu = qkv + base;
  const float* kmu = qkv + base + 1024;
  const float* vp  = qkv + base + 2048;

  const int d0 = tid & 63;
  const int rs = tid >> 6;   // 0..3 (uniform per wave)
  const float2 dt = *(const float2*)&dtab[(h * 64 + d0) * 2];

  // stage Q tile (16 rows x 128 cat-dims), once per block
  #pragma unroll
  for (int i = 0; i < 4; i++) {
    int r = rs + i * 4;
    float mu = qmu[(size_t)(t0 + r) * 3072 + d0];
    const float2 ps = *(const float2*)&postab[((size_t)(t0 + r) * 64 + d0) * 2];
    Qst[d0][r]      = mu * ps.x;
    Qst[d0 + 64][r] = mu * ps.y;
  }

  float m[RPW], l[RPW], o[RPW];
  #pragma unroll
  for (int r = 0; r < RPW; r++) { m[r] = -INFINITY; l[r] = 0.f; o[r] = 0.f; }

  const int myrow0 = t0 + w * RPW;
  const int ntiles = (t0 + QB - 1) / 64 + 1;

  for (int st = 0; st < ntiles; st++) {
    const int s0 = st * 64;
    __syncthreads();   // Q visible (1st iter) / previous compute done
    // stage K (64 x 128) with PoPE phase, and V (64 x 64)
    #pragma unroll
    for (int i = 0; i < 16; i++) {
      int s = rs + i * 4;
      float mu = kmu[(size_t)(s0 + s) * 3072 + d0];
      const float2 ps = *(const float2*)&postab[((size_t)(s0 + s) * 64 + d0) * 2];
      Ks[s][d0]      = mu * (ps.x * dt.x - ps.y * dt.y);
      Ks[s][d0 + 64] = mu * (ps.y * dt.x + ps.x * dt.y);
      Vs[s][d0]      = vp[(size_t)(s0 + s) * 3072 + d0];
    }
    __syncthreads();

    // QK^T: lane = s; 4 rows per wave
    float sc[RPW] = {0.f, 0.f, 0.f, 0.f};
    #pragma unroll 8
    for (int d = 0; d < 128; d++) {
      float kv = Ks[lane][d];
      const float4 q4 = *(const float4*)&Qst[d][w * RPW];
      sc[0] = fmaf(q4.x, kv, sc[0]);
      sc[1] = fmaf(q4.y, kv, sc[1]);
      sc[2] = fmaf(q4.z, kv, sc[2]);
      sc[3] = fmaf(q4.w, kv, sc[3]);
    }

    const int sg = s0 + lane;
    #pragma unroll
    for (int r = 0; r < RPW; r++) {
      float s_r = (sg <= myrow0 + r) ? sc[r] * 0.125f : -INFINITY;
      float mx = s_r;
      #pragma unroll
      for (int off = 32; off > 0; off >>= 1)
        mx = fmaxf(mx, __shfl_xor(mx, off));
      float mn = fmaxf(m[r], mx);
      float p = __expf(s_r - mn);           // exp(-inf) = 0 for masked lanes
      float ps = p;
      #pragma unroll
      for (int off = 32; off > 0; off >>= 1)
        ps += __shfl_xor(ps, off);
      float corr = __expf(m[r] - mn);       // first tile: exp(-inf)=0
      l[r] = l[r] * corr + ps;
      o[r] *= corr;
      m[r] = mn;
      Pst[lane][w * RPW + r] = p;
    }

    // PV: lane = output dim d
    #pragma unroll 8
    for (int s = 0; s < 64; s++) {
      float vv = Vs[s][lane];
      const float4 p4 = *(const float4*)&Pst[s][w * RPW];
      o[0] = fmaf(p4.x, vv, o[0]);
      o[1] = fmaf(p4.y, vv, o[1]);
      o[2] = fmaf(p4.z, vv, o[2]);
      o[3] = fmaf(p4.w, vv, o[3]);
    }
  }

  #pragma unroll
  for (int r = 0; r < RPW; r++)
    y[(size_t)(b * T_ + myrow0 + r) * 1024 + h * 64 + lane] = o[r] / l[r];
}

// ---------------------------------------------------------------------------
extern "C" void kernel_launch(void* const* d_in, const int* in_sizes, int n_in,
                              void* d_out, int out_size, void* d_ws, size_t ws_size,
                              hipStream_t stream)
{
  const float* x      = (const float*)d_in[0];   // (B,T,C)
  const float* w_attn = (const float*)d_in[1];   // (3C,C)
  const float* w_proj = (const float*)d_in[2];   // (C,C)
  const float* delta  = (const float*)d_in[3];   // (H,D)
  float* out = (float*)d_out;                    // (B,T,C) f32

  float* ws = (float*)d_ws;
  float* qkv    = ws;                                    // B*T*3C       = 12,582,912 f
  float* yb     = qkv + (size_t)B_ * T_ * 3 * C_;        // B*T*C        =  4,194,304 f
  float* postab = yb + (size_t)B_ * T_ * C_;             // T*64*2       =    262,144 f
  float* dtab   = postab + (size_t)T_ * 64 * 2;          // H*64*2       =      2,048 f
  // total ~17.04M floats = 68.2 MB

  // 1) qkv = x @ w_attn^T   (M=4096, N=3072, K=1024)
  {
    dim3 grid(3072 / 64, 4096 / 64);
    gemm_nt_f32<<<grid, 256, 0, stream>>>(x, w_attn, qkv, B_ * T_, 3 * C_, C_);
  }
  // 2) softplus in place on q,k thirds
  softplus_inplace<<<(B_ * T_ * 2048) / 256, 256, 0, stream>>>(qkv);
  // 3) trig tables
  build_tables<<<(T_ * 64) / 256, 256, 0, stream>>>(postab, dtab, delta);
  // 4) fused PoPE + causal flash attention -> yb (B,T,C)
  {
    dim3 grid(T_ / QB, H_, B_);
    attn_f32<<<grid, 256, 0, stream>>>(qkv, postab, dtab, yb);
  }
  // 5) out = yb @ w_proj^T  (M=4096, N=1024, K=1024)
  {
    dim3 grid(1024 / 64, 4096 / 64);
    gemm_nt_f32<<<grid, 256, 0, stream>>>(yb, w_proj, out, B_ * T_, C_, C_);
  }
}

// Round 2
// 248.196 us; speedup vs baseline: 6.5565x; 6.5565x over previous
//
#include <hip/hip_runtime.h>
#include <math.h>

typedef short s16x8 __attribute__((ext_vector_type(8)));
typedef float f32x4 __attribute__((ext_vector_type(4)));
typedef unsigned short u16;

#define B_ 2
#define T_ 2048
#define HN_ 16

// ---------------- helpers ----------------
__device__ __forceinline__ u16 f2bf(float f) {
  union { float f; unsigned u; } v; v.f = f;
  unsigned r = v.u + 0x7FFFu + ((v.u >> 16) & 1u);   // RNE (finite inputs)
  return (u16)(r >> 16);
}
__device__ __forceinline__ float bf2f(u16 b) {
  union { unsigned u; float f; } v; v.u = ((unsigned)b) << 16;
  return v.f;
}
__device__ __forceinline__ float softplus_f(float v) {
  return fmaxf(v, 0.f) + log1pf(__expf(-fabsf(v)));
}
__device__ __forceinline__ f32x4 mfma16(s16x8 a, s16x8 b, f32x4 c) {
  return __builtin_amdgcn_mfma_f32_16x16x32_bf16(a, b, c, 0, 0, 0);
}
__device__ __forceinline__ void gload16(void* lds, const void* g) {
  __builtin_amdgcn_global_load_lds(
      (const __attribute__((address_space(1))) unsigned int*)g,
      (__attribute__((address_space(3))) unsigned int*)lds, 16, 0, 0);
}

// ---------------- f32 -> bf16 convert with GEMM-tile swizzle ----------------
// Row length K=1024. Within each 64-elem k-slice (8 chunks of 8 elems),
// chunk' = chunk ^ (row & 7). Consumed by gemm_nt_mfma via linear LDS copy.
__global__ __launch_bounds__(256) void conv_swz(
    const float* __restrict__ in, u16* __restrict__ out, int nchunks)
{
  int c = blockIdx.x * 256 + threadIdx.x;
  if (c >= nchunks) return;
  int row = c >> 7, cc = c & 127;           // 128 chunks per 1024-elem row
  int ks = cc >> 3, ch = cc & 7;
  const float4* src = (const float4*)(in + ((size_t)row << 10) + (cc << 3));
  float4 a = src[0], b = src[1];
  s16x8 o;
  o[0] = (short)f2bf(a.x); o[1] = (short)f2bf(a.y);
  o[2] = (short)f2bf(a.z); o[3] = (short)f2bf(a.w);
  o[4] = (short)f2bf(b.x); o[5] = (short)f2bf(b.y);
  o[6] = (short)f2bf(b.z); o[7] = (short)f2bf(b.w);
  *(s16x8*)(out + ((size_t)row << 10) + (ks << 6) + ((ch ^ (row & 7)) << 3)) = o;
}

// ---------------- trig tables (f32) ----------------
__global__ __launch_bounds__(256) void build_tables(
    float* __restrict__ postab, float* __restrict__ dtab,
    const float* __restrict__ delta)
{
  int idx = blockIdx.x * 256 + threadIdx.x;   // < T_*64
  int t = idx >> 6, d = idx & 63;
  float invf = powf(10000.f, -(float)d * (1.0f / 64.0f));
  float ang = (float)t * invf;
  float sp, cp;
  sincosf(ang, &sp, &cp);
  postab[idx * 2 + 0] = cp;
  postab[idx * 2 + 1] = sp;
  if (idx < HN_ * 64) {
    float dl = delta[idx];
    dl = fminf(fmaxf(dl, -6.2831853071795865f), 0.f);
    float sd, cd;
    sincosf(dl, &sd, &cd);
    dtab[idx * 2 + 0] = cd;
    dtab[idx * 2 + 1] = sd;
  }
}

// ---------------- bf16 MFMA GEMM (NT): C = A * B^T ----------------
// A: MxK bf16 (pre-swizzled), Bw: NxK bf16 (pre-swizzled), K=1024.
// 128x128 tile, BK=64, 4 waves (2x2), per wave 4x4 frags of 16x16x32.
// OUTK=0: bf16 plain out; OUTK=1: f32 plain out.
template<int OUTK>
__global__ __launch_bounds__(256) void gemm_nt_mfma(
    const u16* __restrict__ A, const u16* __restrict__ Bw,
    void* __restrict__ Cout, int N)
{
  __shared__ u16 As[128 * 64];
  __shared__ u16 Bs[128 * 64];
  const int tid = threadIdx.x;
  const int w = tid >> 6, l = tid & 63, g = l >> 4;
  const int bm = blockIdx.y * 128, bn = blockIdx.x * 128;
  const int wr = w >> 1, wc = w & 1;
  const int K = 1024;

  const f32x4 zero = {0.f, 0.f, 0.f, 0.f};
  f32x4 acc[4][4];
  #pragma unroll
  for (int mt = 0; mt < 4; ++mt)
    #pragma unroll
    for (int nt = 0; nt < 4; ++nt) acc[mt][nt] = zero;

  for (int kt = 0; kt < K; kt += 64) {
    __syncthreads();
    #pragma unroll
    for (int j = 0; j < 4; ++j) {
      int cid = (j * 4 + w) * 64 + l;           // chunk 0..1023
      int row = cid >> 3, cc = cid & 7;
      gload16(As + ((j * 4 + w) << 9), A  + (size_t)(bm + row) * K + kt + cc * 8);
      gload16(Bs + ((j * 4 + w) << 9), Bw + (size_t)(bn + row) * K + kt + cc * 8);
    }
    __syncthreads();
    #pragma unroll
    for (int ks = 0; ks < 2; ++ks) {
      s16x8 af[4], bfr[4];
      #pragma unroll
      for (int mt = 0; mt < 4; ++mt) {
        int rr = wr * 64 + mt * 16 + (l & 15);
        af[mt] = *(const s16x8*)(As + rr * 64 + (((ks * 4 + g) ^ (rr & 7)) << 3));
      }
      #pragma unroll
      for (int nt = 0; nt < 4; ++nt) {
        int rr = wc * 64 + nt * 16 + (l & 15);
        bfr[nt] = *(const s16x8*)(Bs + rr * 64 + (((ks * 4 + g) ^ (rr & 7)) << 3));
      }
      #pragma unroll
      for (int mt = 0; mt < 4; ++mt)
        #pragma unroll
        for (int nt = 0; nt < 4; ++nt)
          acc[mt][nt] = mfma16(af[mt], bfr[nt], acc[mt][nt]);
    }
  }

  #pragma unroll
  for (int mt = 0; mt < 4; ++mt)
    #pragma unroll
    for (int nt = 0; nt < 4; ++nt)
      #pragma unroll
      for (int r = 0; r < 4; ++r) {
        int row = bm + wr * 64 + mt * 16 + g * 4 + r;
        int col = bn + wc * 64 + nt * 16 + (l & 15);
        if (OUTK == 0)
          ((u16*)Cout)[(size_t)row * N + col] = f2bf(acc[mt][nt][r]);
        else
          ((float*)Cout)[(size_t)row * N + col] = acc[mt][nt][r];
      }
}

// ---------------- PoPE prepass ----------------
// Kp (B,H,T,128) bf16: K with phases, swizzled (chunk16B ^ (t&7) within row).
// Vtp (B,H,64,T) bf16: V transposed, swizzled (chunk ^ (d&7) within 64-s slice).
__global__ __launch_bounds__(256) void pope_prep(
    const u16* __restrict__ qkvb, const float* __restrict__ postab,
    const float* __restrict__ dtab, u16* __restrict__ Kp, u16* __restrict__ Vtp)
{
  __shared__ u16 Vs[64][72];
  const int tb = blockIdx.x, h = blockIdx.y, b = blockIdx.z;
  const int t0 = tb * 64, tid = threadIdx.x;
  const int tl = tid >> 2, j = tid & 3, d0 = j * 16;
  const int t = t0 + tl;
  const size_t bh = (size_t)b * HN_ + h;
  const size_t qrow = (size_t)(b * T_ + t) * 3072 + h * 64;

  // ---- K with phases, swizzled ----
  {
    s16x8 k0 = *(const s16x8*)(qkvb + qrow + 1024 + d0);
    s16x8 k1 = *(const s16x8*)(qkvb + qrow + 1024 + d0 + 8);
    const float2* pt = (const float2*)postab + (size_t)t * 64 + d0;
    const float2* dt = (const float2*)dtab + h * 64 + d0;
    s16x8 r0, r1, i0, i1;
    #pragma unroll
    for (int i = 0; i < 8; ++i) {
      float mu = softplus_f(bf2f((u16)k0[i]));
      float2 cs = pt[i]; float2 dc = dt[i];
      r0[i] = (short)f2bf(mu * (cs.x * dc.x - cs.y * dc.y));
      i0[i] = (short)f2bf(mu * (cs.y * dc.x + cs.x * dc.y));
    }
    #pragma unroll
    for (int i = 0; i < 8; ++i) {
      float mu = softplus_f(bf2f((u16)k1[i]));
      float2 cs = pt[8 + i]; float2 dc = dt[8 + i];
      r1[i] = (short)f2bf(mu * (cs.x * dc.x - cs.y * dc.y));
      i1[i] = (short)f2bf(mu * (cs.y * dc.x + cs.x * dc.y));
    }
    u16* Krow = Kp + (bh * T_ + t) * 128;
    int sw = t & 7;
    int c0 = d0 >> 3;
    *(s16x8*)(Krow + ((c0 ^ sw) << 3))       = r0;
    *(s16x8*)(Krow + (((c0 + 1) ^ sw) << 3)) = r1;
    *(s16x8*)(Krow + (((c0 + 8) ^ sw) << 3)) = i0;
    *(s16x8*)(Krow + (((c0 + 9) ^ sw) << 3)) = i1;
  }

  // ---- V transpose via LDS ----
  {
    s16x8 v0 = *(const s16x8*)(qkvb + qrow + 2048 + d0);
    s16x8 v1 = *(const s16x8*)(qkvb + qrow + 2048 + d0 + 8);
    *(s16x8*)(&Vs[tl][d0])     = v0;
    *(s16x8*)(&Vs[tl][d0 + 8]) = v1;
  }
  __syncthreads();
  {
    const int d = tid >> 2, jj = tid & 3, ts0 = jj * 16;
    u16* Vrow = Vtp + (bh * 64 + d) * T_;
    int swd = d & 7;
    s16x8 o0, o1;
    #pragma unroll
    for (int i = 0; i < 8; ++i) {
      o0[i] = (short)Vs[ts0 + i][d];
      o1[i] = (short)Vs[ts0 + 8 + i][d];
    }
    int cc0 = ts0 >> 3;
    *(s16x8*)(Vrow + t0 + ((cc0 ^ swd) << 3))       = o0;
    *(s16x8*)(Vrow + t0 + (((cc0 + 1) ^ swd) << 3)) = o1;
  }
}

// ---------------- MFMA flash attention ----------------
// Block: 4 waves; wave w owns q-rows [t0+w*16, +16). s-tile = 64 keys.
// Q frags built on the fly (softplus + pos phase); K/Vt staged via
// global_load_lds from pre-swizzled Kp/Vtp. Online softmax on C frags.
__global__ __launch_bounds__(256) void attn_mfma(
    const u16* __restrict__ qkvb, const u16* __restrict__ Kp,
    const u16* __restrict__ Vtp, const float* __restrict__ postab,
    u16* __restrict__ yb)
{
  __shared__ u16 smem[16384];                // 32 KB
  u16* Ks  = smem;                           // [64][128] swizzled (16 KB)
  u16* Vts = smem + 8192;                    // [64][64]  swizzled (8 KB)
  const int qt = blockIdx.x, h = blockIdx.y, b = blockIdx.z;
  const int tid = threadIdx.x, w = tid >> 6, l = tid & 63, g = l >> 4;
  const int t0 = qt * 64;
  const size_t bh = (size_t)b * HN_ + h;
  u16* Pw = smem + 12288 + w * 1024;         // per-wave P [16][64] swizzled (2 KB)

  // ---- Q fragments (4 k-steps of 32 over cat-dim 128) ----
  s16x8 qf[4];
  {
    const int qr = t0 + w * 16 + (l & 15);
    const u16* qrp = qkvb + (size_t)(b * T_ + qr) * 3072 + h * 64;
    const float2* pt = (const float2*)postab + (size_t)qr * 64;
    #pragma unroll
    for (int f = 0; f < 4; ++f) {
      int c0 = f * 32 + g * 8;
      int half = c0 >> 6, d0 = c0 & 63;
      s16x8 mu8 = *(const s16x8*)(qrp + d0);
      s16x8 qv;
      #pragma unroll
      for (int i = 0; i < 8; ++i) {
        float mu = softplus_f(bf2f((u16)mu8[i]));
        float2 cs = pt[d0 + i];
        qv[i] = (short)f2bf(mu * (half ? cs.y : cs.x));
      }
      qf[f] = qv;
    }
  }

  const f32x4 zero = {0.f, 0.f, 0.f, 0.f};
  f32x4 o[4];
  float m[4], ll[4];
  #pragma unroll
  for (int i = 0; i < 4; ++i) { o[i] = zero; m[i] = -3e38f; ll[i] = 0.f; }

  const u16* Kpb = Kp + bh * T_ * 128;
  const u16* Vtb = Vtp + bh * 64 * T_;

  for (int st = 0; st <= qt; ++st) {
    const int s0 = st * 64;
    __syncthreads();
    // ---- stage K (16 KB) + Vt (8 KB), linear copies of pre-swizzled rows ----
    #pragma unroll
    for (int j = 0; j < 4; ++j) {
      int cid = (j * 4 + w) * 64 + l;          // 0..1023
      int row = cid >> 4, cc = cid & 15;
      gload16(Ks + ((j * 4 + w) << 9), Kpb + (size_t)(s0 + row) * 128 + cc * 8);
    }
    #pragma unroll
    for (int j = 0; j < 2; ++j) {
      int cid = (j * 4 + w) * 64 + l;          // 0..511
      int row = cid >> 3, cc = cid & 7;
      gload16(Vts + ((j * 4 + w) << 9), Vtb + (size_t)row * T_ + s0 + cc * 8);
    }
    __syncthreads();

    // ---- QK^T: 16 MFMA ----
    f32x4 sacc[4];
    #pragma unroll
    for (int nt = 0; nt < 4; ++nt) sacc[nt] = zero;
    #pragma unroll
    for (int ks = 0; ks < 4; ++ks)
      #pragma unroll
      for (int nt = 0; nt < 4; ++nt) {
        int srow = nt * 16 + (l & 15);
        s16x8 kf = *(const s16x8*)(Ks + srow * 128 + (((ks * 4 + g) ^ (srow & 7)) << 3));
        sacc[nt] = mfma16(qf[ks], kf, sacc[nt]);
      }

    // ---- online softmax on C frags (rows q = g*4+r, cols s = nt*16 + (l&15)) ----
    const bool diag = (st == qt);
    float sc[4][4];
    #pragma unroll
    for (int nt = 0; nt < 4; ++nt)
      #pragma unroll
      for (int r = 0; r < 4; ++r) {
        float v = sacc[nt][r] * 0.125f;
        if (diag && (s0 + nt * 16 + (l & 15)) > (t0 + w * 16 + g * 4 + r)) v = -3e38f;
        sc[nt][r] = v;
      }
    float p[4][4];
    #pragma unroll
    for (int r = 0; r < 4; ++r) {
      float mx = fmaxf(fmaxf(sc[0][r], sc[1][r]), fmaxf(sc[2][r], sc[3][r]));
      mx = fmaxf(mx, __shfl_xor(mx, 1));
      mx = fmaxf(mx, __shfl_xor(mx, 2));
      mx = fmaxf(mx, __shfl_xor(mx, 4));
      mx = fmaxf(mx, __shfl_xor(mx, 8));
      float mn = fmaxf(m[r], mx);
      float corr = __expf(m[r] - mn);
      float rs = 0.f;
      #pragma unroll
      for (int nt = 0; nt < 4; ++nt) {
        float pv = __expf(sc[nt][r] - mn);
        p[nt][r] = pv; rs += pv;
      }
      rs += __shfl_xor(rs, 1);
      rs += __shfl_xor(rs, 2);
      rs += __shfl_xor(rs, 4);
      rs += __shfl_xor(rs, 8);
      ll[r] = ll[r] * corr + rs;
      m[r] = mn;
      o[0][r] *= corr; o[1][r] *= corr; o[2][r] *= corr; o[3][r] *= corr;
    }
    // ---- P -> per-wave LDS (swizzled) ----
    #pragma unroll
    for (int nt = 0; nt < 4; ++nt)
      #pragma unroll
      for (int r = 0; r < 4; ++r) {
        int qrow = g * 4 + r;
        int cs_ = nt * 16 + (l & 15);
        Pw[qrow * 64 + (((cs_ >> 3) ^ (qrow & 7)) << 3) + (cs_ & 7)] = f2bf(p[nt][r]);
      }

    // ---- PV: 8 MFMA ----
    #pragma unroll
    for (int ks = 0; ks < 2; ++ks) {
      int qrow = l & 15;
      s16x8 pa = *(const s16x8*)(Pw + qrow * 64 + (((ks * 4 + g) ^ (qrow & 7)) << 3));
      #pragma unroll
      for (int nt = 0; nt < 4; ++nt) {
        int dr = nt * 16 + (l & 15);
        s16x8 vf = *(const s16x8*)(Vts + dr * 64 + (((ks * 4 + g) ^ (dr & 7)) << 3));
        o[nt] = mfma16(pa, vf, o[nt]);
      }
    }
  }

  // ---- epilogue: yb (plain-per-row but GEMM-swizzled chunk positions) ----
  #pragma unroll
  for (int r = 0; r < 4; ++r) {
    float inv = 1.0f / ll[r];
    int qr = t0 + w * 16 + g * 4 + r;
    size_t rb = (size_t)(b * T_ + qr) * 1024;
    #pragma unroll
    for (int nt = 0; nt < 4; ++nt) {
      int col = h * 64 + nt * 16 + (l & 15);
      int ch = (col & 63) >> 3;
      yb[rb + (col & ~63) + ((ch ^ (qr & 7)) << 3) + (col & 7)] = f2bf(o[nt][r] * inv);
    }
  }
}

// ---------------------------------------------------------------------------
extern "C" void kernel_launch(void* const* d_in, const int* in_sizes, int n_in,
                              void* d_out, int out_size, void* d_ws, size_t ws_size,
                              hipStream_t stream)
{
  const float* x      = (const float*)d_in[0];   // (B,T,C)
  const float* w_attn = (const float*)d_in[1];   // (3C,C)
  const float* w_proj = (const float*)d_in[2];   // (C,C)
  const float* delta  = (const float*)d_in[3];   // (H,D)
  float* out = (float*)d_out;

  char* p = (char*)d_ws;
  u16* xb     = (u16*)p;  p += (size_t)4096 * 1024 * 2;        // swizzled bf16 x
  u16* wab    = (u16*)p;  p += (size_t)3072 * 1024 * 2;        // swizzled bf16 w_attn
  u16* wpb    = (u16*)p;  p += (size_t)1024 * 1024 * 2;        // swizzled bf16 w_proj
  u16* qkvb   = (u16*)p;  p += (size_t)4096 * 3072 * 2;        // plain bf16 qkv
  u16* yb     = (u16*)p;  p += (size_t)4096 * 1024 * 2;        // swizzled bf16 y
  u16* Kp     = (u16*)p;  p += (size_t)B_ * HN_ * T_ * 128 * 2; // swizzled K+phase
  u16* Vtp    = (u16*)p;  p += (size_t)B_ * HN_ * 64 * T_ * 2;  // swizzled V^T
  float* postab = (float*)p; p += (size_t)T_ * 64 * 2 * 4;
  float* dtab   = (float*)p; p += (size_t)HN_ * 64 * 2 * 4;

  conv_swz<<<(4096 * 128) / 256, 256, 0, stream>>>(x, xb, 4096 * 128);
  conv_swz<<<(3072 * 128) / 256, 256, 0, stream>>>(w_attn, wab, 3072 * 128);
  conv_swz<<<(1024 * 128) / 256, 256, 0, stream>>>(w_proj, wpb, 1024 * 128);
  build_tables<<<(T_ * 64) / 256, 256, 0, stream>>>(postab, dtab, delta);

  gemm_nt_mfma<0><<<dim3(3072 / 128, 4096 / 128), 256, 0, stream>>>(xb, wab, qkvb, 3072);
  pope_prep<<<dim3(T_ / 64, HN_, B_), 256, 0, stream>>>(qkvb, postab, dtab, Kp, Vtp);
  attn_mfma<<<dim3(T_ / 64, HN_, B_), 256, 0, stream>>>(qkvb, Kp, Vtp, postab, yb);
  gemm_nt_mfma<1><<<dim3(1024 / 128, 4096 / 128), 256, 0, stream>>>(yb, wpb, out, 1024);
}

// Round 3
// 194.855 us; speedup vs baseline: 8.3514x; 1.2738x over previous
//
#include <hip/hip_runtime.h>
#include <math.h>

typedef short s16x8 __attribute__((ext_vector_type(8)));
typedef float f32x4 __attribute__((ext_vector_type(4)));
typedef float f32x16 __attribute__((ext_vector_type(16)));
typedef unsigned short u16;

#define B_ 2
#define T_ 2048
#define HN_ 16

// ---------------- helpers ----------------
__device__ __forceinline__ u16 f2bf(float f) {
  union { float f; unsigned u; } v; v.f = f;
  unsigned r = v.u + 0x7FFFu + ((v.u >> 16) & 1u);   // RNE (finite inputs)
  return (u16)(r >> 16);
}
__device__ __forceinline__ float bf2f(u16 b) {
  union { unsigned u; float f; } v; v.u = ((unsigned)b) << 16;
  return v.f;
}
__device__ __forceinline__ float softplus_f(float v) {
  return fmaxf(v, 0.f) + log1pf(__expf(-fabsf(v)));
}
__device__ __forceinline__ f32x4 mfma16(s16x8 a, s16x8 b, f32x4 c) {
  return __builtin_amdgcn_mfma_f32_16x16x32_bf16(a, b, c, 0, 0, 0);
}
__device__ __forceinline__ f32x16 mfma32(s16x8 a, s16x8 b, f32x16 c) {
  return __builtin_amdgcn_mfma_f32_32x32x16_bf16(a, b, c, 0, 0, 0);
}
__device__ __forceinline__ void gload16(void* lds, const void* g) {
  __builtin_amdgcn_global_load_lds(
      (const __attribute__((address_space(1))) unsigned int*)g,
      (__attribute__((address_space(3))) unsigned int*)lds, 16, 0, 0);
}
__device__ __forceinline__ unsigned cvtpk(float lo, float hi) {
  unsigned r;
  asm("v_cvt_pk_bf16_f32 %0, %1, %2" : "=v"(r) : "v"(lo), "v"(hi));
  return r;
}

// ---------------- f32 -> bf16 convert with GEMM-tile swizzle ----------------
__global__ __launch_bounds__(256) void conv_swz(
    const float* __restrict__ in, u16* __restrict__ out, int nchunks)
{
  int c = blockIdx.x * 256 + threadIdx.x;
  if (c >= nchunks) return;
  int row = c >> 7, cc = c & 127;           // 128 chunks per 1024-elem row
  int ks = cc >> 3, ch = cc & 7;
  const float4* src = (const float4*)(in + ((size_t)row << 10) + (cc << 3));
  float4 a = src[0], b = src[1];
  s16x8 o;
  o[0] = (short)f2bf(a.x); o[1] = (short)f2bf(a.y);
  o[2] = (short)f2bf(a.z); o[3] = (short)f2bf(a.w);
  o[4] = (short)f2bf(b.x); o[5] = (short)f2bf(b.y);
  o[6] = (short)f2bf(b.z); o[7] = (short)f2bf(b.w);
  *(s16x8*)(out + ((size_t)row << 10) + (ks << 6) + ((ch ^ (row & 7)) << 3)) = o;
}

// ---------------- trig tables (f32) ----------------
__global__ __launch_bounds__(256) void build_tables(
    float* __restrict__ postab, float* __restrict__ dtab,
    const float* __restrict__ delta)
{
  int idx = blockIdx.x * 256 + threadIdx.x;   // < T_*64
  int t = idx >> 6, d = idx & 63;
  float invf = powf(10000.f, -(float)d * (1.0f / 64.0f));
  float ang = (float)t * invf;
  float sp, cp;
  sincosf(ang, &sp, &cp);
  postab[idx * 2 + 0] = cp;
  postab[idx * 2 + 1] = sp;
  if (idx < HN_ * 64) {
    float dl = delta[idx];
    dl = fminf(fmaxf(dl, -6.2831853071795865f), 0.f);
    float sd, cd;
    sincosf(dl, &sd, &cd);
    dtab[idx * 2 + 0] = cd;
    dtab[idx * 2 + 1] = sd;
  }
}

// ---------------- bf16 MFMA GEMM (NT): C = A * B^T ----------------
template<int OUTK>
__global__ __launch_bounds__(256) void gemm_nt_mfma(
    const u16* __restrict__ A, const u16* __restrict__ Bw,
    void* __restrict__ Cout, int N)
{
  __shared__ u16 As[128 * 64];
  __shared__ u16 Bs[128 * 64];
  const int tid = threadIdx.x;
  const int w = tid >> 6, l = tid & 63, g = l >> 4;
  const int bm = blockIdx.y * 128, bn = blockIdx.x * 128;
  const int wr = w >> 1, wc = w & 1;
  const int K = 1024;

  const f32x4 zero = {0.f, 0.f, 0.f, 0.f};
  f32x4 acc[4][4];
  #pragma unroll
  for (int mt = 0; mt < 4; ++mt)
    #pragma unroll
    for (int nt = 0; nt < 4; ++nt) acc[mt][nt] = zero;

  for (int kt = 0; kt < K; kt += 64) {
    __syncthreads();
    #pragma unroll
    for (int j = 0; j < 4; ++j) {
      int cid = (j * 4 + w) * 64 + l;           // chunk 0..1023
      int row = cid >> 3, cc = cid & 7;
      gload16(As + ((j * 4 + w) << 9), A  + (size_t)(bm + row) * K + kt + cc * 8);
      gload16(Bs + ((j * 4 + w) << 9), Bw + (size_t)(bn + row) * K + kt + cc * 8);
    }
    __syncthreads();
    #pragma unroll
    for (int ks = 0; ks < 2; ++ks) {
      s16x8 af[4], bfr[4];
      #pragma unroll
      for (int mt = 0; mt < 4; ++mt) {
        int rr = wr * 64 + mt * 16 + (l & 15);
        af[mt] = *(const s16x8*)(As + rr * 64 + (((ks * 4 + g) ^ (rr & 7)) << 3));
      }
      #pragma unroll
      for (int nt = 0; nt < 4; ++nt) {
        int rr = wc * 64 + nt * 16 + (l & 15);
        bfr[nt] = *(const s16x8*)(Bs + rr * 64 + (((ks * 4 + g) ^ (rr & 7)) << 3));
      }
      #pragma unroll
      for (int mt = 0; mt < 4; ++mt)
        #pragma unroll
        for (int nt = 0; nt < 4; ++nt)
          acc[mt][nt] = mfma16(af[mt], bfr[nt], acc[mt][nt]);
    }
  }

  #pragma unroll
  for (int mt = 0; mt < 4; ++mt)
    #pragma unroll
    for (int nt = 0; nt < 4; ++nt)
      #pragma unroll
      for (int r = 0; r < 4; ++r) {
        int row = bm + wr * 64 + mt * 16 + g * 4 + r;
        int col = bn + wc * 64 + nt * 16 + (l & 15);
        if (OUTK == 0)
          ((u16*)Cout)[(size_t)row * N + col] = f2bf(acc[mt][nt][r]);
        else
          ((float*)Cout)[(size_t)row * N + col] = acc[mt][nt][r];
      }
}

// ---------------- PoPE prepass (Kp swizzled, Vt swizzled) ----------------
__global__ __launch_bounds__(256) void pope_prep(
    const u16* __restrict__ qkvb, const float* __restrict__ postab,
    const float* __restrict__ dtab, u16* __restrict__ Kp, u16* __restrict__ Vtp)
{
  __shared__ u16 Vs[64][72];
  const int tb = blockIdx.x, h = blockIdx.y, b = blockIdx.z;
  const int t0 = tb * 64, tid = threadIdx.x;
  const int tl = tid >> 2, j = tid & 3, d0 = j * 16;
  const int t = t0 + tl;
  const size_t bh = (size_t)b * HN_ + h;
  const size_t qrow = (size_t)(b * T_ + t) * 3072 + h * 64;

  {
    s16x8 k0 = *(const s16x8*)(qkvb + qrow + 1024 + d0);
    s16x8 k1 = *(const s16x8*)(qkvb + qrow + 1024 + d0 + 8);
    const float2* pt = (const float2*)postab + (size_t)t * 64 + d0;
    const float2* dt = (const float2*)dtab + h * 64 + d0;
    s16x8 r0, r1, i0, i1;
    #pragma unroll
    for (int i = 0; i < 8; ++i) {
      float mu = softplus_f(bf2f((u16)k0[i]));
      float2 cs = pt[i]; float2 dc = dt[i];
      r0[i] = (short)f2bf(mu * (cs.x * dc.x - cs.y * dc.y));
      i0[i] = (short)f2bf(mu * (cs.y * dc.x + cs.x * dc.y));
    }
    #pragma unroll
    for (int i = 0; i < 8; ++i) {
      float mu = softplus_f(bf2f((u16)k1[i]));
      float2 cs = pt[8 + i]; float2 dc = dt[8 + i];
      r1[i] = (short)f2bf(mu * (cs.x * dc.x - cs.y * dc.y));
      i1[i] = (short)f2bf(mu * (cs.y * dc.x + cs.x * dc.y));
    }
    u16* Krow = Kp + (bh * T_ + t) * 128;
    int sw = t & 7;
    int c0 = d0 >> 3;
    *(s16x8*)(Krow + ((c0 ^ sw) << 3))       = r0;
    *(s16x8*)(Krow + (((c0 + 1) ^ sw) << 3)) = r1;
    *(s16x8*)(Krow + (((c0 + 8) ^ sw) << 3)) = i0;
    *(s16x8*)(Krow + (((c0 + 9) ^ sw) << 3)) = i1;
  }

  {
    s16x8 v0 = *(const s16x8*)(qkvb + qrow + 2048 + d0);
    s16x8 v1 = *(const s16x8*)(qkvb + qrow + 2048 + d0 + 8);
    *(s16x8*)(&Vs[tl][d0])     = v0;
    *(s16x8*)(&Vs[tl][d0 + 8]) = v1;
  }
  __syncthreads();
  {
    const int d = tid >> 2, jj = tid & 3, ts0 = jj * 16;
    u16* Vrow = Vtp + (bh * 64 + d) * T_;
    int swd = d & 7;
    s16x8 o0, o1;
    #pragma unroll
    for (int i = 0; i < 8; ++i) {
      o0[i] = (short)Vs[ts0 + i][d];
      o1[i] = (short)Vs[ts0 + 8 + i][d];
    }
    int cc0 = ts0 >> 3;
    *(s16x8*)(Vrow + t0 + ((cc0 ^ swd) << 3))       = o0;
    *(s16x8*)(Vrow + t0 + (((cc0 + 1) ^ swd) << 3)) = o1;
  }
}

// ---------------- MFMA flash attention, 32x32 swapped-QK^T ----------------
// 4 waves x 32 q-rows = 128 q-rows/block. KV tile = 64.
// Swapped QK^T: sacc = mfma(K, Q) -> C[s][q], col=q=lane&31 -> P row in regs.
// Softmax fully in-register (exp2 domain, defer-max). P->A-frag via cvt_pk +
// shfl_xor(32). PV: o = mfma(P, V) -> C[q][d].
__global__ __launch_bounds__(256) void attn_mfma32(
    const u16* __restrict__ qkvb, const u16* __restrict__ Kp,
    const u16* __restrict__ Vtp, const float* __restrict__ postab,
    u16* __restrict__ yb)
{
  __shared__ u16 smem[12288];                // 24 KB
  u16* Ks  = smem;                           // [64][128] swizzled (16 KB)
  u16* Vts = smem + 8192;                    // [64][64]  swizzled (8 KB)
  const int h = blockIdx.y, b = blockIdx.z;
  const int qt = (int)gridDim.x - 1 - (int)blockIdx.x;   // heavy blocks first
  const int Qb = qt * 128;
  const int tid = threadIdx.x, w = tid >> 6, l = tid & 63;
  const int hi = l >> 5, ln = l & 31;
  const size_t bh = (size_t)b * HN_ + h;

  const float LS = 0.125f * 1.4426950408889634f;   // scale * log2(e)
  const float THRL = 11.5f;                        // defer-max threshold (log2)

  // ---- Q fragments: 8 k-steps of 16 over cat-dim 128 (B-operand layout) ----
  const int q = Qb + w * 32 + ln;
  s16x8 qf[8];
  {
    const u16* qrp = qkvb + (size_t)(b * T_ + q) * 3072 + h * 64;
    const float2* pt = (const float2*)postab + (size_t)q * 64;
    #pragma unroll
    for (int kb = 0; kb < 4; ++kb) {
      int d0 = kb * 16 + hi * 8;
      s16x8 mu8 = *(const s16x8*)(qrp + d0);
      #pragma unroll
      for (int i = 0; i < 8; ++i) {
        float mu = softplus_f(bf2f((u16)mu8[i]));
        float2 cs = pt[d0 + i];
        qf[kb][i]     = (short)f2bf(mu * cs.x);
        qf[kb + 4][i] = (short)f2bf(mu * cs.y);
      }
    }
  }

  const f32x16 zero16 = {0.f,0.f,0.f,0.f,0.f,0.f,0.f,0.f,
                         0.f,0.f,0.f,0.f,0.f,0.f,0.f,0.f};
  f32x16 o0 = zero16, o1 = zero16;
  float m = -3e38f, lsum = 0.f;

  const u16* Kpb = Kp + bh * T_ * 128;
  const u16* Vtb = Vtp + bh * 64 * T_;
  const int ntiles = 2 * qt + 2;

  for (int st = 0; st < ntiles; ++st) {
    const int s0 = st * 64;
    __syncthreads();
    // ---- stage K (16 KB) + Vt (8 KB): linear copies of pre-swizzled rows ----
    #pragma unroll
    for (int j = 0; j < 4; ++j) {
      int cid = (j * 4 + w) * 64 + l;          // 0..1023
      int row = cid >> 4, cc = cid & 15;
      gload16(Ks + ((j * 4 + w) << 9), Kpb + (size_t)(s0 + row) * 128 + cc * 8);
    }
    #pragma unroll
    for (int j = 0; j < 2; ++j) {
      int cid = (j * 4 + w) * 64 + l;          // 0..511
      int row = cid >> 3, cc = cid & 7;
      gload16(Vts + ((j * 4 + w) << 9), Vtb + (size_t)row * T_ + s0 + cc * 8);
    }
    __syncthreads();

    const bool active = s0 <= (Qb + w * 32 + 31);
    if (active) {
      const bool needmask = (s0 + 63) > (Qb + w * 32);

      // ---- QK^T (swapped): sacc[a] = K[a-subtile] x Q, C[s][q] ----
      f32x16 sacc0 = zero16, sacc1 = zero16;
      #pragma unroll
      for (int ks = 0; ks < 8; ++ks) {
        int r0_ = ln, r1_ = 32 + ln;
        s16x8 kf0 = *(const s16x8*)(Ks + r0_ * 128 + (((2 * ks + hi) ^ (r0_ & 7)) << 3));
        s16x8 kf1 = *(const s16x8*)(Ks + r1_ * 128 + (((2 * ks + hi) ^ (r1_ & 7)) << 3));
        sacc0 = mfma32(kf0, qf[ks], sacc0);
        sacc1 = mfma32(kf1, qf[ks], sacc1);
      }

      // ---- masked scores ----
      float sc[2][16];
      #pragma unroll
      for (int j = 0; j < 16; ++j) { sc[0][j] = sacc0[j]; sc[1][j] = sacc1[j]; }
      if (needmask) {
        #pragma unroll
        for (int a = 0; a < 2; ++a)
          #pragma unroll
          for (int j = 0; j < 16; ++j) {
            int sg = s0 + a * 32 + (j & 3) + 8 * (j >> 2) + 4 * hi;
            if (sg > q) sc[a][j] = -3e38f;
          }
      }

      // ---- online softmax (log2 domain) ----
      float pm = -3e38f;
      #pragma unroll
      for (int j = 0; j < 16; ++j) pm = fmaxf(pm, fmaxf(sc[0][j], sc[1][j]));
      pm = fmaxf(pm, __shfl_xor(pm, 32));
      float pmax = pm * LS;

      if (__any(pmax > m + THRL)) {
        float mnew = fmaxf(m, pmax);
        float corr = exp2f(m - mnew);
        m = mnew;
        lsum *= corr;
        #pragma unroll
        for (int j = 0; j < 16; ++j) {
          float cj = __shfl(corr, (j & 3) + 8 * (j >> 2) + 4 * hi);
          o0[j] *= cj; o1[j] *= cj;
        }
      }

      float pv[2][16];
      float rs = 0.f;
      #pragma unroll
      for (int a = 0; a < 2; ++a)
        #pragma unroll
        for (int j = 0; j < 16; ++j) {
          float p = exp2f(fmaf(sc[a][j], LS, -m));
          pv[a][j] = p; rs += p;
        }
      rs += __shfl_xor(rs, 32);
      lsum += rs;

      // ---- P -> bf16 A-frags (in-register redistribution) ----
      s16x8 pa[4];
      #pragma unroll
      for (int ks = 0; ks < 4; ++ks) {
        const int a = ks >> 1, bb = (ks & 1) * 8;
        unsigned pk01 = cvtpk(pv[a][bb + 0], pv[a][bb + 1]);
        unsigned pk23 = cvtpk(pv[a][bb + 2], pv[a][bb + 3]);
        unsigned pk45 = cvtpk(pv[a][bb + 4], pv[a][bb + 5]);
        unsigned pk67 = cvtpk(pv[a][bb + 6], pv[a][bb + 7]);
        unsigned sv0 = hi ? pk01 : pk45;
        unsigned sv1 = hi ? pk23 : pk67;
        unsigned r0 = (unsigned)__shfl_xor((int)sv0, 32);
        unsigned r1 = (unsigned)__shfl_xor((int)sv1, 32);
        union { unsigned u[4]; s16x8 v; } pu;
        pu.u[0] = hi ? r0 : pk01;
        pu.u[1] = hi ? r1 : pk23;
        pu.u[2] = hi ? pk45 : r0;
        pu.u[3] = hi ? pk67 : r1;
        pa[ks] = pu.v;
      }

      // ---- PV: o[q][d] += P x V ----
      #pragma unroll
      for (int ks = 0; ks < 4; ++ks) {
        int rd0 = ln, rd1 = 32 + ln;
        s16x8 vb0 = *(const s16x8*)(Vts + rd0 * 64 + (((2 * ks + hi) ^ (rd0 & 7)) << 3));
        s16x8 vb1 = *(const s16x8*)(Vts + rd1 * 64 + (((2 * ks + hi) ^ (rd1 & 7)) << 3));
        o0 = mfma32(pa[ks], vb0, o0);
        o1 = mfma32(pa[ks], vb1, o1);
      }
    }
  }

  // ---- epilogue: divide by l, store swizzled bf16 ----
  float linv = 1.0f / lsum;
  #pragma unroll
  for (int j = 0; j < 16; ++j) {
    float lj = __shfl(linv, (j & 3) + 8 * (j >> 2) + 4 * hi);
    int qrow = Qb + w * 32 + (j & 3) + 8 * (j >> 2) + 4 * hi;
    size_t rb = (size_t)(b * T_ + qrow) * 1024 + h * 64;
    #pragma unroll
    for (int nt = 0; nt < 2; ++nt) {
      int dcol = nt * 32 + ln;
      float val = (nt ? o1[j] : o0[j]) * lj;
      int ch = dcol >> 3;
      yb[rb + ((ch ^ (qrow & 7)) << 3) + (dcol & 7)] = f2bf(val);
    }
  }
}

// ---------------------------------------------------------------------------
extern "C" void kernel_launch(void* const* d_in, const int* in_sizes, int n_in,
                              void* d_out, int out_size, void* d_ws, size_t ws_size,
                              hipStream_t stream)
{
  const float* x      = (const float*)d_in[0];   // (B,T,C)
  const float* w_attn = (const float*)d_in[1];   // (3C,C)
  const float* w_proj = (const float*)d_in[2];   // (C,C)
  const float* delta  = (const float*)d_in[3];   // (H,D)
  float* out = (float*)d_out;

  char* p = (char*)d_ws;
  u16* xb     = (u16*)p;  p += (size_t)4096 * 1024 * 2;
  u16* wab    = (u16*)p;  p += (size_t)3072 * 1024 * 2;
  u16* wpb    = (u16*)p;  p += (size_t)1024 * 1024 * 2;
  u16* qkvb   = (u16*)p;  p += (size_t)4096 * 3072 * 2;
  u16* yb     = (u16*)p;  p += (size_t)4096 * 1024 * 2;
  u16* Kp     = (u16*)p;  p += (size_t)B_ * HN_ * T_ * 128 * 2;
  u16* Vtp    = (u16*)p;  p += (size_t)B_ * HN_ * 64 * T_ * 2;
  float* postab = (float*)p; p += (size_t)T_ * 64 * 2 * 4;
  float* dtab   = (float*)p; p += (size_t)HN_ * 64 * 2 * 4;

  conv_swz<<<(4096 * 128) / 256, 256, 0, stream>>>(x, xb, 4096 * 128);
  conv_swz<<<(3072 * 128) / 256, 256, 0, stream>>>(w_attn, wab, 3072 * 128);
  conv_swz<<<(1024 * 128) / 256, 256, 0, stream>>>(w_proj, wpb, 1024 * 128);
  build_tables<<<(T_ * 64) / 256, 256, 0, stream>>>(postab, dtab, delta);

  gemm_nt_mfma<0><<<dim3(3072 / 128, 4096 / 128), 256, 0, stream>>>(xb, wab, qkvb, 3072);
  pope_prep<<<dim3(T_ / 64, HN_, B_), 256, 0, stream>>>(qkvb, postab, dtab, Kp, Vtp);
  attn_mfma32<<<dim3(T_ / 128, HN_, B_), 256, 0, stream>>>(qkvb, Kp, Vtp, postab, yb);
  gemm_nt_mfma<1><<<dim3(1024 / 128, 4096 / 128), 256, 0, stream>>>(yb, wpb, out, 1024);
}